// Round 4
// baseline (673.928 us; speedup 1.0000x reference)
//
#include <hip/hip_runtime.h>
#include <hip/hip_bf16.h>

#define N_NODES 50000
#define N_EDGES 800000
#define N_TOT   850000   // edges + self loops

typedef __hip_bfloat16 bf16;

__device__ __forceinline__ float b2f(bf16 v){ return __bfloat162float(v); }
__device__ __forceinline__ bf16  f2b(float v){ return __float2bfloat16(v); }

// ---------------- CSR build (group edges by destination = col) ----------------
__global__ __launch_bounds__(256) void hist_kernel(const int* __restrict__ ei, int* __restrict__ cnt){
  int k = blockIdx.x*256 + threadIdx.x;
  if (k >= N_TOT) return;
  int c = (k < N_EDGES) ? ei[N_EDGES + k] : (k - N_EDGES);
  atomicAdd(&cnt[c], 1);
}

__global__ __launch_bounds__(1024) void scan_kernel(const int* __restrict__ cnt,
                                                    int* __restrict__ offs,
                                                    int* __restrict__ cursor){
  __shared__ int sm[1024];
  __shared__ int carry_s;
  int tid = threadIdx.x;
  if (tid == 0) carry_s = 0;
  __syncthreads();
  for (int base = 0; base < N_NODES; base += 1024) {
    int i = base + tid;
    int v = (i < N_NODES) ? cnt[i] : 0;
    sm[tid] = v;
    __syncthreads();
    for (int off = 1; off < 1024; off <<= 1) {
      int t = (tid >= off) ? sm[tid - off] : 0;
      __syncthreads();
      sm[tid] += t;
      __syncthreads();
    }
    int incl  = sm[tid];
    int carry = carry_s;
    __syncthreads();                 // everyone reads carry before it's updated
    if (i < N_NODES) { int e = carry + incl - v; offs[i] = e; cursor[i] = e; }
    if (tid == 1023) carry_s = carry + incl;
    __syncthreads();
  }
  if (tid == 0) offs[N_NODES] = carry_s;   // == N_TOT
}

__global__ __launch_bounds__(256) void scatter_kernel(const int* __restrict__ ei,
                                                      int* __restrict__ cursor,
                                                      int* __restrict__ srcs){
  int k = blockIdx.x*256 + threadIdx.x;
  if (k >= N_TOT) return;
  int r, c;
  if (k < N_EDGES) { r = ei[k]; c = ei[N_EDGES + k]; } else { r = c = k - N_EDGES; }
  int pos = atomicAdd(&cursor[c], 1);
  srcs[pos] = r;
}

// ---------------- GEMM1: h1pre = x @ W1  [50000,64]x[64,256], fused al1 ----------------
__global__ __launch_bounds__(256) void gemm1_kernel(const float* __restrict__ x, const float* __restrict__ W1,
    const float* __restrict__ a1s, const float* __restrict__ a1d,
    bf16* __restrict__ h1pre, float* __restrict__ al1s, float* __restrict__ al1d){
  __shared__ __align__(16) float lx[64*8];          // [k][m]
  int tid = threadIdx.x;
  int n0  = blockIdx.x * 8;
  for (int i = tid; i < 512; i += 256) {
    int m = i >> 6, k = i & 63;
    lx[k*8 + m] = x[(size_t)(n0 + m)*64 + k];
  }
  __syncthreads();
  float acc[8] = {0,0,0,0,0,0,0,0};
  #pragma unroll 4
  for (int k = 0; k < 64; k++) {
    float w = W1[k*256 + tid];
    const float4* xp = (const float4*)&lx[k*8];
    float4 xa = xp[0], xb = xp[1];
    acc[0] = fmaf(w, xa.x, acc[0]);
    acc[1] = fmaf(w, xa.y, acc[1]);
    acc[2] = fmaf(w, xa.z, acc[2]);
    acc[3] = fmaf(w, xa.w, acc[3]);
    acc[4] = fmaf(w, xb.x, acc[4]);
    acc[5] = fmaf(w, xb.y, acc[5]);
    acc[6] = fmaf(w, xb.z, acc[6]);
    acc[7] = fmaf(w, xb.w, acc[7]);
  }
  float as = a1s[tid], ad = a1d[tid];
  int lane = tid & 63, wave = tid >> 6;   // wave == head
  #pragma unroll
  for (int m = 0; m < 8; m++) {
    h1pre[(size_t)(n0 + m)*256 + tid] = f2b(acc[m]);
    float ps = acc[m]*as, pd = acc[m]*ad;
    #pragma unroll
    for (int off = 32; off; off >>= 1) { ps += __shfl_xor(ps, off, 64); pd += __shfl_xor(pd, off, 64); }
    if (lane == 0) { al1s[(n0 + m)*4 + wave] = ps; al1d[(n0 + m)*4 + wave] = pd; }
  }
}

// ------- Attention layer 1 (H=4,C=64) FUSED with GEMM2 + al2 reductions -------
// wave per node; h1 row never hits global memory (LDS only).
__global__ __launch_bounds__(256) void attn1f_kernel(const bf16* __restrict__ h1pre,
    const float* __restrict__ al1s, const float* __restrict__ al1d,
    const int* __restrict__ offs, const int* __restrict__ srcs,
    const float* __restrict__ b1, const float* __restrict__ W2,
    const float* __restrict__ a2s, const float* __restrict__ a2d,
    bf16* __restrict__ h2pre, float* __restrict__ al2s, float* __restrict__ al2d){
  __shared__ __align__(16) float sh1[4][256];
  int wave = threadIdx.x >> 6, lane = threadIdx.x & 63;
  int n = blockIdx.x*4 + wave;          // 50000 % 4 == 0: no tail
  int start = offs[n], end = offs[n+1];
  float4 aldv = *(const float4*)(al1d + (size_t)n*4);
  float ald0 = aldv.x, ald1 = aldv.y, ald2 = aldv.z, ald3 = aldv.w;

  float mx0 = -3e38f, mx1 = -3e38f, mx2 = -3e38f, mx3 = -3e38f;
  for (int j = start + lane; j < end; j += 64) {
    int r = srcs[j];
    float4 als = *(const float4*)(al1s + (size_t)r*4);
    float e0 = als.x + ald0; e0 = e0 >= 0.f ? e0 : 0.2f*e0; mx0 = fmaxf(mx0, e0);
    float e1 = als.y + ald1; e1 = e1 >= 0.f ? e1 : 0.2f*e1; mx1 = fmaxf(mx1, e1);
    float e2 = als.z + ald2; e2 = e2 >= 0.f ? e2 : 0.2f*e2; mx2 = fmaxf(mx2, e2);
    float e3 = als.w + ald3; e3 = e3 >= 0.f ? e3 : 0.2f*e3; mx3 = fmaxf(mx3, e3);
  }
  #pragma unroll
  for (int off = 32; off; off >>= 1) {
    mx0 = fmaxf(mx0, __shfl_xor(mx0, off, 64));
    mx1 = fmaxf(mx1, __shfl_xor(mx1, off, 64));
    mx2 = fmaxf(mx2, __shfl_xor(mx2, off, 64));
    mx3 = fmaxf(mx3, __shfl_xor(mx3, off, 64));
  }
  float s0 = 0.f, s1 = 0.f, s2 = 0.f, s3 = 0.f;
  for (int j = start + lane; j < end; j += 64) {
    int r = srcs[j];
    float4 als = *(const float4*)(al1s + (size_t)r*4);
    float e0 = als.x + ald0; e0 = e0 >= 0.f ? e0 : 0.2f*e0; s0 += __expf(e0 - mx0);
    float e1 = als.y + ald1; e1 = e1 >= 0.f ? e1 : 0.2f*e1; s1 += __expf(e1 - mx1);
    float e2 = als.z + ald2; e2 = e2 >= 0.f ? e2 : 0.2f*e2; s2 += __expf(e2 - mx2);
    float e3 = als.w + ald3; e3 = e3 >= 0.f ? e3 : 0.2f*e3; s3 += __expf(e3 - mx3);
  }
  #pragma unroll
  for (int off = 32; off; off >>= 1) {
    s0 += __shfl_xor(s0, off, 64);
    s1 += __shfl_xor(s1, off, 64);
    s2 += __shfl_xor(s2, off, 64);
    s3 += __shfl_xor(s3, off, 64);
  }
  float inv0 = 1.f/(s0 + 1e-16f), inv1 = 1.f/(s1 + 1e-16f);
  float inv2 = 1.f/(s2 + 1e-16f), inv3 = 1.f/(s3 + 1e-16f);

  float a0 = 0.f, a1 = 0.f, a2 = 0.f, a3 = 0.f;  // lane = channel c
  for (int j = start; j < end; ++j) {
    int r = srcs[j];
    float4 als = *(const float4*)(al1s + (size_t)r*4);
    const bf16* hr = h1pre + (size_t)r*256 + lane;
    float e0 = als.x + ald0; e0 = e0 >= 0.f ? e0 : 0.2f*e0;
    float e1 = als.y + ald1; e1 = e1 >= 0.f ? e1 : 0.2f*e1;
    float e2 = als.z + ald2; e2 = e2 >= 0.f ? e2 : 0.2f*e2;
    float e3 = als.w + ald3; e3 = e3 >= 0.f ? e3 : 0.2f*e3;
    a0 = fmaf(__expf(e0 - mx0)*inv0, b2f(hr[0]),   a0);
    a1 = fmaf(__expf(e1 - mx1)*inv1, b2f(hr[64]),  a1);
    a2 = fmaf(__expf(e2 - mx2)*inv2, b2f(hr[128]), a2);
    a3 = fmaf(__expf(e3 - mx3)*inv3, b2f(hr[192]), a3);
  }
  // h1 row for node n (post-bias ELU), staged to LDS
  float o0 = a0 + b1[lane];       o0 = o0 > 0.f ? o0 : expm1f(o0);
  float o1 = a1 + b1[64 + lane];  o1 = o1 > 0.f ? o1 : expm1f(o1);
  float o2 = a2 + b1[128 + lane]; o2 = o2 > 0.f ? o2 : expm1f(o2);
  float o3 = a3 + b1[192 + lane]; o3 = o3 > 0.f ? o3 : expm1f(o3);
  float* s1p = sh1[wave];
  s1p[lane] = o0; s1p[64 + lane] = o1; s1p[128 + lane] = o2; s1p[192 + lane] = o3;
  __syncthreads();

  // GEMM2 row: h2pre[n][lane] = sum_k h1[n][k] * W2[k*64+lane]
  float acc = 0.f;
  #pragma unroll 8
  for (int k = 0; k < 256; k++)
    acc = fmaf(s1p[k], W2[k*64 + lane], acc);
  h2pre[(size_t)n*64 + lane] = f2b(acc);

  float ps = acc * a2s[lane], pd = acc * a2d[lane];
  #pragma unroll
  for (int off = 32; off; off >>= 1) { ps += __shfl_xor(ps, off, 64); pd += __shfl_xor(pd, off, 64); }
  if (lane == 0) { al2s[n] = ps; al2d[n] = pd; }
}

// ---------------- Attention layer 2 (H=1) + node head + u/v for edge head ----------------
__global__ __launch_bounds__(256) void attn2_kernel(const bf16* __restrict__ h2pre,
    const float* __restrict__ al2s, const float* __restrict__ al2d,
    const int* __restrict__ offs, const int* __restrict__ srcs,
    const float* __restrict__ b2, const float* __restrict__ Wn, const float* __restrict__ bn,
    const float* __restrict__ We,
    float* __restrict__ u, float* __restrict__ v, float* __restrict__ node_out){
  __shared__ float sh[4][64];
  int wave = threadIdx.x >> 6, lane = threadIdx.x & 63;
  int n = blockIdx.x*4 + wave;          // exact
  int start = offs[n], end = offs[n+1];
  float ald = al2d[n];

  float mx = -3e38f;
  for (int j = start + lane; j < end; j += 64) {
    float t = al2s[srcs[j]] + ald; t = t >= 0.f ? t : 0.2f*t;
    mx = fmaxf(mx, t);
  }
  #pragma unroll
  for (int off = 32; off; off >>= 1) mx = fmaxf(mx, __shfl_xor(mx, off, 64));
  float sm = 0.f;
  for (int j = start + lane; j < end; j += 64) {
    float t = al2s[srcs[j]] + ald; t = t >= 0.f ? t : 0.2f*t;
    sm += __expf(t - mx);
  }
  #pragma unroll
  for (int off = 32; off; off >>= 1) sm += __shfl_xor(sm, off, 64);
  float inv = 1.f/(sm + 1e-16f);

  float acc = 0.f;
  for (int j = start; j < end; ++j) {
    int r = srcs[j];
    float t = al2s[r] + ald; t = t >= 0.f ? t : 0.2f*t;
    acc = fmaf(__expf(t - mx)*inv, b2f(h2pre[(size_t)r*64 + lane]), acc);
  }
  float o = acc + b2[lane];
  o = o > 0.f ? o : expm1f(o);          // h2 value, lane = channel

  // u[n] = h2 . We[0:64], v[n] = h2 . We[64:128]
  float pu = o * We[lane];
  float pv = o * We[64 + lane];
  #pragma unroll
  for (int off = 32; off; off >>= 1) { pu += __shfl_xor(pu, off, 64); pv += __shfl_xor(pv, off, 64); }
  if (lane == 0) { u[n] = pu; v[n] = pv; }

  sh[wave][lane] = o;
  __syncthreads();

  // node_out = h2 @ Wn + bn  (Wn: [64,32]); lanes split k-range in halves
  int jcol = lane & 31, half = lane >> 5;
  float a2 = 0.f;
  #pragma unroll 8
  for (int k2 = 0; k2 < 32; k2++) {
    int k = half*32 + k2;
    a2 = fmaf(sh[wave][k], Wn[k*32 + jcol], a2);
  }
  a2 += __shfl_xor(a2, 32, 64);
  if (lane < 32) node_out[(size_t)n*32 + lane] = a2 + bn[jcol];
}

// ---------------- Edge head: out = u[row] + v[col] + edge_attr . We[128:144] + be ----------------
__global__ __launch_bounds__(256) void edge_kernel(const int* __restrict__ ei, const float* __restrict__ ea,
    const float* __restrict__ u, const float* __restrict__ v,
    const float* __restrict__ We, const float* __restrict__ be, float* __restrict__ out){
  int k = blockIdx.x*256 + threadIdx.x;   // grid is exact: 800000/256
  int r = ei[k], c = ei[N_EDGES + k];
  float val = u[r] + v[c] + be[0];
  const float4* wp = (const float4*)(We + 128);
  const float4* p  = (const float4*)(ea + (size_t)k*16);
  #pragma unroll
  for (int jj = 0; jj < 4; jj++) {
    float4 q = p[jj], wq = wp[jj];
    val = fmaf(q.x, wq.x, val);
    val = fmaf(q.y, wq.y, val);
    val = fmaf(q.z, wq.z, val);
    val = fmaf(q.w, wq.w, val);
  }
  out[k] = val;
}

extern "C" void kernel_launch(void* const* d_in, const int* in_sizes, int n_in,
                              void* d_out, int out_size, void* d_ws, size_t ws_size,
                              hipStream_t stream) {
  const float* x   = (const float*)d_in[0];
  const int*   ei  = (const int*)d_in[1];
  const float* ea  = (const float*)d_in[2];
  const float* W1  = (const float*)d_in[3];
  const float* a1s = (const float*)d_in[4];
  const float* a1d = (const float*)d_in[5];
  const float* b1  = (const float*)d_in[6];
  const float* W2  = (const float*)d_in[7];
  const float* a2s = (const float*)d_in[8];
  const float* a2d = (const float*)d_in[9];
  const float* b2  = (const float*)d_in[10];
  const float* Wn  = (const float*)d_in[11];
  const float* bn  = (const float*)d_in[12];
  const float* We  = (const float*)d_in[13];
  const float* be  = (const float*)d_in[14];
  float* out = (float*)d_out;

  // ---- workspace layout, peak 38,400,016 B (~36.6 MiB), all offsets 16B-aligned ----
  char* w = (char*)d_ws;
  int*   offs   = (int*)(w);                        //       0 .. 200,016
  int*   cnt    = (int*)(w + 200016);               // 200,016 .. 400,016
  int*   cursor = (int*)(w + 400016);               // 400,016 .. 600,016
  int*   srcs   = (int*)(w + 600016);               // 600,016 .. 4,000,016
  float* al1s   = (float*)(w + 4000016);            // [N,4] fp32, .. 4,800,016
  float* al1d   = (float*)(w + 4800016);            // [N,4] fp32, .. 5,600,016
  float* al2s   = (float*)(w + 5600016);            // [N] fp32,  .. 5,800,016
  float* al2d   = (float*)(w + 5800016);            // .. 6,000,016
  float* uu     = (float*)(w + 6000016);            // .. 6,200,016
  float* vv     = (float*)(w + 6200016);            // .. 6,400,016
  bf16*  h2pre  = (bf16*)(w + 6400016);             // [N,64] bf16, .. 12,800,016
  bf16*  h1pre  = (bf16*)(w + 12800016);            // [N,256] bf16, .. 38,400,016

  hipMemsetAsync(cnt, 0, (size_t)N_NODES * 4, stream);
  hist_kernel   <<<(N_TOT + 255)/256, 256, 0, stream>>>(ei, cnt);
  scan_kernel   <<<1, 1024, 0, stream>>>(cnt, offs, cursor);
  scatter_kernel<<<(N_TOT + 255)/256, 256, 0, stream>>>(ei, cursor, srcs);
  gemm1_kernel  <<<N_NODES/8, 256, 0, stream>>>(x, W1, a1s, a1d, h1pre, al1s, al1d);
  attn1f_kernel <<<N_NODES/4, 256, 0, stream>>>(h1pre, al1s, al1d, offs, srcs, b1, W2,
                                                a2s, a2d, h2pre, al2s, al2d);
  attn2_kernel  <<<N_NODES/4, 256, 0, stream>>>(h2pre, al2s, al2d, offs, srcs, b2, Wn, bn, We,
                                                uu, vv, out);
  edge_kernel   <<<N_EDGES/256, 256, 0, stream>>>(ei, ea, uu, vv, We, be, out + (size_t)N_NODES*32);
}

// Round 5
// 451.083 us; speedup vs baseline: 1.4940x; 1.4940x over previous
//
#include <hip/hip_runtime.h>
#include <hip/hip_bf16.h>

#define N_NODES 50000
#define N_EDGES 800000
#define N_TOT   850000   // edges + self loops
#define MAXD    128      // LDS-staged edges per node; tail handled by fallback

typedef __hip_bfloat16 bf16;

__device__ __forceinline__ float b2f(bf16 v){ return __bfloat162float(v); }
__device__ __forceinline__ bf16  f2b(float v){ return __float2bfloat16(v); }

// ---------------- CSR build (group edges by destination = col) ----------------
__global__ __launch_bounds__(256) void hist_kernel(const int* __restrict__ ei, int* __restrict__ cnt){
  int k = blockIdx.x*256 + threadIdx.x;
  if (k >= N_TOT) return;
  int c = (k < N_EDGES) ? ei[N_EDGES + k] : (k - N_EDGES);
  atomicAdd(&cnt[c], 1);
}

// hierarchical scan: A) per-1024-block sums  B) scan 49 partials  C) per-block scan + base
__global__ __launch_bounds__(1024) void scanA_kernel(const int* __restrict__ cnt, int* __restrict__ psum){
  __shared__ int wsum[16];
  int tid = threadIdx.x, i = blockIdx.x*1024 + tid;
  int v = (i < N_NODES) ? cnt[i] : 0;
  #pragma unroll
  for (int off = 32; off; off >>= 1) v += __shfl_xor(v, off, 64);
  if ((tid & 63) == 0) wsum[tid >> 6] = v;
  __syncthreads();
  if (tid < 64) {
    int t = (tid < 16) ? wsum[tid] : 0;
    #pragma unroll
    for (int off = 8; off; off >>= 1) t += __shfl_xor(t, off, 64);
    if (tid == 0) psum[blockIdx.x] = t;
  }
}

__global__ __launch_bounds__(64) void scanB_kernel(int* __restrict__ psum, int nparts){
  int lane = threadIdx.x;
  int v = (lane < nparts) ? psum[lane] : 0;
  #pragma unroll
  for (int off = 1; off < 64; off <<= 1) {
    int t = __shfl_up(v, off, 64);
    if (lane >= off) v += t;
  }
  int e = __shfl_up(v, 1, 64);
  if (lane == 0) e = 0;
  if (lane < nparts) psum[lane] = e;
}

__global__ __launch_bounds__(1024) void scanC_kernel(const int* __restrict__ cnt, const int* __restrict__ psum,
                                                     int* __restrict__ offs, int* __restrict__ cursor){
  __shared__ int sm[1024];
  int tid = threadIdx.x, b = blockIdx.x, i = b*1024 + tid;
  int v = (i < N_NODES) ? cnt[i] : 0;
  sm[tid] = v;
  __syncthreads();
  for (int off = 1; off < 1024; off <<= 1) {
    int t = (tid >= off) ? sm[tid - off] : 0;
    __syncthreads();
    sm[tid] += t;
    __syncthreads();
  }
  if (i < N_NODES) {
    int e = psum[b] + sm[tid] - v;
    offs[i] = e; cursor[i] = e;
  }
  if (b == 0 && tid == 0) offs[N_NODES] = N_TOT;
}

__global__ __launch_bounds__(256) void scatter_kernel(const int* __restrict__ ei,
                                                      int* __restrict__ cursor,
                                                      int* __restrict__ srcs){
  int k = blockIdx.x*256 + threadIdx.x;
  if (k >= N_TOT) return;
  int r, c;
  if (k < N_EDGES) { r = ei[k]; c = ei[N_EDGES + k]; } else { r = c = k - N_EDGES; }
  int pos = atomicAdd(&cursor[c], 1);
  srcs[pos] = r;
}

// ---------------- GEMM1: h1pre = x @ W1  [50000,64]x[64,256], fused al1, 16 nodes/block ----------------
__global__ __launch_bounds__(256) void gemm1_kernel(const float* __restrict__ x, const float* __restrict__ W1,
    const float* __restrict__ a1s, const float* __restrict__ a1d,
    bf16* __restrict__ h1pre, float* __restrict__ al1s, float* __restrict__ al1d){
  __shared__ __align__(16) float lx[64*16];          // [k][m], 4KB
  int tid = threadIdx.x;
  int n0  = blockIdx.x * 16;
  for (int i = tid; i < 1024; i += 256) {
    int m = i >> 6, k = i & 63;
    lx[k*16 + m] = x[(size_t)(n0 + m)*64 + k];
  }
  __syncthreads();
  float acc[16];
  #pragma unroll
  for (int m = 0; m < 16; m++) acc[m] = 0.f;
  #pragma unroll 2
  for (int k = 0; k < 64; k++) {
    float w = W1[k*256 + tid];
    const float4* xp = (const float4*)&lx[k*16];
    #pragma unroll
    for (int q = 0; q < 4; q++) {
      float4 xa = xp[q];
      acc[4*q+0] = fmaf(w, xa.x, acc[4*q+0]);
      acc[4*q+1] = fmaf(w, xa.y, acc[4*q+1]);
      acc[4*q+2] = fmaf(w, xa.z, acc[4*q+2]);
      acc[4*q+3] = fmaf(w, xa.w, acc[4*q+3]);
    }
  }
  float as = a1s[tid], ad = a1d[tid];
  int lane = tid & 63, wave = tid >> 6;   // wave == head
  #pragma unroll
  for (int m = 0; m < 16; m++) {
    h1pre[(size_t)(n0 + m)*256 + tid] = f2b(acc[m]);
    float ps = acc[m]*as, pd = acc[m]*ad;
    #pragma unroll
    for (int off = 32; off; off >>= 1) { ps += __shfl_xor(ps, off, 64); pd += __shfl_xor(pd, off, 64); }
    if (lane == 0) { al1s[(n0 + m)*4 + wave] = ps; al1d[(n0 + m)*4 + wave] = pd; }
  }
}

// ------- Attention layer 1 (H=4,C=64) + split-K GEMM2 + al2; 8 waves / 8 nodes per block -------
__global__ __launch_bounds__(512) void attn1_kernel(const bf16* __restrict__ h1pre,
    const float* __restrict__ al1s, const float* __restrict__ al1d,
    const int* __restrict__ offs, const int* __restrict__ srcs,
    const float* __restrict__ b1, const float* __restrict__ W2,
    const float* __restrict__ a2s, const float* __restrict__ a2d,
    bf16* __restrict__ h2pre, float* __restrict__ al2s, float* __restrict__ al2d){
  __shared__ __align__(16) float sh1[8][256];            // 8KB: h1 rows
  __shared__ __align__(16) float upool[8*MAXD*4];        // 16KB: ebuf, then gemm partials
  __shared__ int sbuf[8][MAXD];                          // 4KB: staged srcs
  float (*ebuf)[MAXD][4] = (float (*)[MAXD][4])upool;
  float (*pbuf)[8][64]   = (float (*)[8][64])upool;

  int wave = threadIdx.x >> 6, lane = threadIdx.x & 63;
  int n = blockIdx.x*8 + wave;          // 50000 % 8 == 0: no tail
  int start = offs[n], end = offs[n+1];
  int deg = end - start;
  float4 aldv = *(const float4*)(al1d + (size_t)n*4);
  float ald0 = aldv.x, ald1 = aldv.y, ald2 = aldv.z, ald3 = aldv.w;

  // pass1: gather als, compute e (lrelu), stage e + src, online lane max
  float mx0 = -3e38f, mx1 = -3e38f, mx2 = -3e38f, mx3 = -3e38f;
  {
    int idx = lane;
    for (int j = start + lane; j < end; j += 64, idx += 64) {
      int r = srcs[j];
      float4 als = *(const float4*)(al1s + (size_t)r*4);
      float e0 = als.x + ald0; e0 = e0 >= 0.f ? e0 : 0.2f*e0; mx0 = fmaxf(mx0, e0);
      float e1 = als.y + ald1; e1 = e1 >= 0.f ? e1 : 0.2f*e1; mx1 = fmaxf(mx1, e1);
      float e2 = als.z + ald2; e2 = e2 >= 0.f ? e2 : 0.2f*e2; mx2 = fmaxf(mx2, e2);
      float e3 = als.w + ald3; e3 = e3 >= 0.f ? e3 : 0.2f*e3; mx3 = fmaxf(mx3, e3);
      if (idx < MAXD) {
        sbuf[wave][idx] = r;
        float* ep = &ebuf[wave][idx][0];
        ep[0] = e0; ep[1] = e1; ep[2] = e2; ep[3] = e3;
      }
    }
  }
  #pragma unroll
  for (int off = 32; off; off >>= 1) {
    mx0 = fmaxf(mx0, __shfl_xor(mx0, off, 64));
    mx1 = fmaxf(mx1, __shfl_xor(mx1, off, 64));
    mx2 = fmaxf(mx2, __shfl_xor(mx2, off, 64));
    mx3 = fmaxf(mx3, __shfl_xor(mx3, off, 64));
  }

  // pass2: p = exp(e - m) written back; lane sums
  float s0 = 0.f, s1 = 0.f, s2 = 0.f, s3 = 0.f;
  {
    int lim = deg < MAXD ? deg : MAXD;
    for (int idx = lane; idx < lim; idx += 64) {
      float* ep = &ebuf[wave][idx][0];
      float p0 = __expf(ep[0] - mx0); ep[0] = p0; s0 += p0;
      float p1 = __expf(ep[1] - mx1); ep[1] = p1; s1 += p1;
      float p2 = __expf(ep[2] - mx2); ep[2] = p2; s2 += p2;
      float p3 = __expf(ep[3] - mx3); ep[3] = p3; s3 += p3;
    }
    for (int j = start + MAXD + lane; j < end; j += 64) {  // rare overflow tail
      int r = srcs[j];
      float4 als = *(const float4*)(al1s + (size_t)r*4);
      float e0 = als.x + ald0; e0 = e0 >= 0.f ? e0 : 0.2f*e0; s0 += __expf(e0 - mx0);
      float e1 = als.y + ald1; e1 = e1 >= 0.f ? e1 : 0.2f*e1; s1 += __expf(e1 - mx1);
      float e2 = als.z + ald2; e2 = e2 >= 0.f ? e2 : 0.2f*e2; s2 += __expf(e2 - mx2);
      float e3 = als.w + ald3; e3 = e3 >= 0.f ? e3 : 0.2f*e3; s3 += __expf(e3 - mx3);
    }
  }
  #pragma unroll
  for (int off = 32; off; off >>= 1) {
    s0 += __shfl_xor(s0, off, 64);
    s1 += __shfl_xor(s1, off, 64);
    s2 += __shfl_xor(s2, off, 64);
    s3 += __shfl_xor(s3, off, 64);
  }
  float inv0 = 1.f/(s0 + 1e-16f), inv1 = 1.f/(s1 + 1e-16f);
  float inv2 = 1.f/(s2 + 1e-16f), inv3 = 1.f/(s3 + 1e-16f);

  // serial aggregation: p broadcast from LDS + gathered h1pre rows; inv folded at end
  float a0 = 0.f, a1 = 0.f, a2 = 0.f, a3 = 0.f;  // lane = channel c
  {
    int lim = deg < MAXD ? deg : MAXD;
    for (int jj = 0; jj < lim; ++jj) {
      int r = sbuf[wave][jj];
      float4 p = *(const float4*)&ebuf[wave][jj][0];
      const bf16* hr = h1pre + (size_t)r*256 + lane;
      a0 = fmaf(p.x, b2f(hr[0]),   a0);
      a1 = fmaf(p.y, b2f(hr[64]),  a1);
      a2 = fmaf(p.z, b2f(hr[128]), a2);
      a3 = fmaf(p.w, b2f(hr[192]), a3);
    }
    for (int jj = MAXD; jj < deg; ++jj) {   // rare overflow tail
      int r = srcs[start + jj];
      float4 als = *(const float4*)(al1s + (size_t)r*4);
      const bf16* hr = h1pre + (size_t)r*256 + lane;
      float e0 = als.x + ald0; e0 = e0 >= 0.f ? e0 : 0.2f*e0;
      float e1 = als.y + ald1; e1 = e1 >= 0.f ? e1 : 0.2f*e1;
      float e2 = als.z + ald2; e2 = e2 >= 0.f ? e2 : 0.2f*e2;
      float e3 = als.w + ald3; e3 = e3 >= 0.f ? e3 : 0.2f*e3;
      a0 = fmaf(__expf(e0 - mx0), b2f(hr[0]),   a0);
      a1 = fmaf(__expf(e1 - mx1), b2f(hr[64]),  a1);
      a2 = fmaf(__expf(e2 - mx2), b2f(hr[128]), a2);
      a3 = fmaf(__expf(e3 - mx3), b2f(hr[192]), a3);
    }
  }
  // h1 row (post-bias ELU) into LDS
  float o0 = a0*inv0 + b1[lane];       o0 = o0 > 0.f ? o0 : expm1f(o0);
  float o1 = a1*inv1 + b1[64 + lane];  o1 = o1 > 0.f ? o1 : expm1f(o1);
  float o2 = a2*inv2 + b1[128 + lane]; o2 = o2 > 0.f ? o2 : expm1f(o2);
  float o3 = a3*inv3 + b1[192 + lane]; o3 = o3 > 0.f ? o3 : expm1f(o3);
  float* s1p = sh1[wave];
  s1p[lane] = o0; s1p[64 + lane] = o1; s1p[128 + lane] = o2; s1p[192 + lane] = o3;
  __syncthreads();   // sh1 complete; ebuf dead -> pbuf reuse is safe past this point

  // split-K GEMM2: wave w handles k in [w*32, w*32+32); W2 read ONCE per block
  {
    int col = lane, k0 = wave*32;
    float part[8];
    #pragma unroll
    for (int m = 0; m < 8; m++) part[m] = 0.f;
    #pragma unroll
    for (int kk = 0; kk < 32; kk += 4) {
      float w0 = W2[(k0+kk+0)*64 + col];
      float w1 = W2[(k0+kk+1)*64 + col];
      float w2 = W2[(k0+kk+2)*64 + col];
      float w3 = W2[(k0+kk+3)*64 + col];
      #pragma unroll
      for (int m = 0; m < 8; m++) {
        float4 hv = *(const float4*)&sh1[m][k0+kk];
        part[m] = fmaf(hv.x, w0, fmaf(hv.y, w1, fmaf(hv.z, w2, fmaf(hv.w, w3, part[m]))));
      }
    }
    __syncthreads();   // ensure all ebuf readers done before pbuf overwrite (also orders sh1 reads)
    #pragma unroll
    for (int m = 0; m < 8; m++) pbuf[wave][m][col] = part[m];
  }
  __syncthreads();

  // final: wave w owns node w; reduce partials over 8 k-groups
  {
    int col = lane;
    float acc = 0.f;
    #pragma unroll
    for (int g = 0; g < 8; g++) acc += pbuf[g][wave][col];
    h2pre[(size_t)n*64 + col] = f2b(acc);
    float ps = acc * a2s[col], pd = acc * a2d[col];
    #pragma unroll
    for (int off = 32; off; off >>= 1) { ps += __shfl_xor(ps, off, 64); pd += __shfl_xor(pd, off, 64); }
    if (col == 0) { al2s[n] = ps; al2d[n] = pd; }
  }
}

// ---------------- Attention layer 2 (H=1) + node head + u/v; 8 waves/block ----------------
__global__ __launch_bounds__(512) void attn2_kernel(const bf16* __restrict__ h2pre,
    const float* __restrict__ al2s, const float* __restrict__ al2d,
    const int* __restrict__ offs, const int* __restrict__ srcs,
    const float* __restrict__ b2, const float* __restrict__ Wn, const float* __restrict__ bn,
    const float* __restrict__ We,
    float* __restrict__ u, float* __restrict__ v, float* __restrict__ node_out){
  __shared__ float ebuf[8][MAXD];     // 4KB
  __shared__ int   sbuf[8][MAXD];     // 4KB
  __shared__ float sh[8][64];         // 2KB
  int wave = threadIdx.x >> 6, lane = threadIdx.x & 63;
  int n = blockIdx.x*8 + wave;        // exact
  int start = offs[n], end = offs[n+1];
  int deg = end - start;
  float ald = al2d[n];

  float mx = -3e38f;
  {
    int idx = lane;
    for (int j = start + lane; j < end; j += 64, idx += 64) {
      int r = srcs[j];
      float t = al2s[r] + ald; t = t >= 0.f ? t : 0.2f*t;
      mx = fmaxf(mx, t);
      if (idx < MAXD) { sbuf[wave][idx] = r; ebuf[wave][idx] = t; }
    }
  }
  #pragma unroll
  for (int off = 32; off; off >>= 1) mx = fmaxf(mx, __shfl_xor(mx, off, 64));

  float sm = 0.f;
  {
    int lim = deg < MAXD ? deg : MAXD;
    for (int idx = lane; idx < lim; idx += 64) {
      float p = __expf(ebuf[wave][idx] - mx); ebuf[wave][idx] = p; sm += p;
    }
    for (int j = start + MAXD + lane; j < end; j += 64) {
      float t = al2s[srcs[j]] + ald; t = t >= 0.f ? t : 0.2f*t;
      sm += __expf(t - mx);
    }
  }
  #pragma unroll
  for (int off = 32; off; off >>= 1) sm += __shfl_xor(sm, off, 64);
  float inv = 1.f/(sm + 1e-16f);

  float acc = 0.f;
  {
    int lim = deg < MAXD ? deg : MAXD;
    for (int jj = 0; jj < lim; ++jj) {
      int r = sbuf[wave][jj];
      acc = fmaf(ebuf[wave][jj], b2f(h2pre[(size_t)r*64 + lane]), acc);
    }
    for (int jj = MAXD; jj < deg; ++jj) {
      int r = srcs[start + jj];
      float t = al2s[r] + ald; t = t >= 0.f ? t : 0.2f*t;
      acc = fmaf(__expf(t - mx), b2f(h2pre[(size_t)r*64 + lane]), acc);
    }
  }
  float o = acc*inv + b2[lane];
  o = o > 0.f ? o : expm1f(o);          // h2 value, lane = channel

  // u[n] = h2 . We[0:64], v[n] = h2 . We[64:128]
  float pu = o * We[lane];
  float pv = o * We[64 + lane];
  #pragma unroll
  for (int off = 32; off; off >>= 1) { pu += __shfl_xor(pu, off, 64); pv += __shfl_xor(pv, off, 64); }
  if (lane == 0) { u[n] = pu; v[n] = pv; }

  sh[wave][lane] = o;
  __syncthreads();

  // node_out = h2 @ Wn + bn  (Wn: [64,32]); lanes split k-range in halves
  int jcol = lane & 31, half = lane >> 5;
  float a2 = 0.f;
  #pragma unroll 8
  for (int k2 = 0; k2 < 32; k2++) {
    int k = half*32 + k2;
    a2 = fmaf(sh[wave][k], Wn[k*32 + jcol], a2);
  }
  a2 += __shfl_xor(a2, 32, 64);
  if (lane < 32) node_out[(size_t)n*32 + lane] = a2 + bn[jcol];
}

// ---------------- Edge head: out = u[row] + v[col] + edge_attr . We[128:144] + be ----------------
__global__ __launch_bounds__(256) void edge_kernel(const int* __restrict__ ei, const float* __restrict__ ea,
    const float* __restrict__ u, const float* __restrict__ v,
    const float* __restrict__ We, const float* __restrict__ be, float* __restrict__ out){
  int k = blockIdx.x*256 + threadIdx.x;   // grid is exact: 800000/256
  int r = ei[k], c = ei[N_EDGES + k];
  float val = u[r] + v[c] + be[0];
  const float4* wp = (const float4*)(We + 128);
  const float4* p  = (const float4*)(ea + (size_t)k*16);
  #pragma unroll
  for (int jj = 0; jj < 4; jj++) {
    float4 q = p[jj], wq = wp[jj];
    val = fmaf(q.x, wq.x, val);
    val = fmaf(q.y, wq.y, val);
    val = fmaf(q.z, wq.z, val);
    val = fmaf(q.w, wq.w, val);
  }
  out[k] = val;
}

extern "C" void kernel_launch(void* const* d_in, const int* in_sizes, int n_in,
                              void* d_out, int out_size, void* d_ws, size_t ws_size,
                              hipStream_t stream) {
  const float* x   = (const float*)d_in[0];
  const int*   ei  = (const int*)d_in[1];
  const float* ea  = (const float*)d_in[2];
  const float* W1  = (const float*)d_in[3];
  const float* a1s = (const float*)d_in[4];
  const float* a1d = (const float*)d_in[5];
  const float* b1  = (const float*)d_in[6];
  const float* W2  = (const float*)d_in[7];
  const float* a2s = (const float*)d_in[8];
  const float* a2d = (const float*)d_in[9];
  const float* b2  = (const float*)d_in[10];
  const float* Wn  = (const float*)d_in[11];
  const float* bn  = (const float*)d_in[12];
  const float* We  = (const float*)d_in[13];
  const float* be  = (const float*)d_in[14];
  float* out = (float*)d_out;

  // ---- workspace layout, peak 38,400,032 B, all offsets 16B-aligned (known-good size) ----
  char* w = (char*)d_ws;
  int*   offs   = (int*)(w);                        //       0 .. 200,016
  int*   cnt    = (int*)(w + 200016);               // 200,016 .. 400,016
  int*   cursor = (int*)(w + 400016);               // 400,016 .. 600,016
  int*   srcs   = (int*)(w + 600016);               // 600,016 .. 4,000,016
  float* al1s   = (float*)(w + 4000016);            // [N,4] fp32, .. 4,800,016
  float* al1d   = (float*)(w + 4800016);            // [N,4] fp32, .. 5,600,016
  float* al2s   = (float*)(w + 5600016);            // [N] fp32,  .. 5,800,016
  float* al2d   = (float*)(w + 5800016);            // .. 6,000,016
  float* uu     = (float*)(w + 6000016);            // .. 6,200,016
  float* vv     = (float*)(w + 6200016);            // .. 6,400,016
  bf16*  h2pre  = (bf16*)(w + 6400016);             // [N,64] bf16, .. 12,800,016
  bf16*  h1pre  = (bf16*)(w + 12800016);            // [N,256] bf16, .. 38,400,016
  int*   psum   = (int*)(w + 38400016);             // 49 partials (reuses slack; 16B-aligned)

  const int NPART = (N_NODES + 1023) / 1024;        // 49

  hipMemsetAsync(cnt, 0, (size_t)N_NODES * 4, stream);
  hist_kernel   <<<(N_TOT + 255)/256, 256, 0, stream>>>(ei, cnt);
  scanA_kernel  <<<NPART, 1024, 0, stream>>>(cnt, psum);
  scanB_kernel  <<<1, 64, 0, stream>>>(psum, NPART);
  scanC_kernel  <<<NPART, 1024, 0, stream>>>(cnt, psum, offs, cursor);
  scatter_kernel<<<(N_TOT + 255)/256, 256, 0, stream>>>(ei, cursor, srcs);
  gemm1_kernel  <<<N_NODES/16, 256, 0, stream>>>(x, W1, a1s, a1d, h1pre, al1s, al1d);
  attn1_kernel  <<<N_NODES/8, 512, 0, stream>>>(h1pre, al1s, al1d, offs, srcs, b1, W2,
                                                a2s, a2d, h2pre, al2s, al2d);
  attn2_kernel  <<<N_NODES/8, 512, 0, stream>>>(h2pre, al2s, al2d, offs, srcs, b2, Wn, bn, We,
                                                uu, vv, out);
  edge_kernel   <<<N_EDGES/256, 256, 0, stream>>>(ei, ea, uu, vv, We, be, out + (size_t)N_NODES*32);
}

// Round 6
// 442.075 us; speedup vs baseline: 1.5245x; 1.0204x over previous
//
#include <hip/hip_runtime.h>
#include <hip/hip_bf16.h>

#define N_NODES 50000
#define N_EDGES 800000
#define N_TOT   850000   // edges + self loops
#define MAXD    128      // LDS-staged edges per node; tail handled by fallback

typedef __hip_bfloat16 bf16;

__device__ __forceinline__ float b2f(bf16 v){ return __bfloat162float(v); }
__device__ __forceinline__ bf16  f2b(float v){ return __float2bfloat16(v); }
__device__ __forceinline__ float bflo(unsigned int d){ return __uint_as_float(d << 16); }
__device__ __forceinline__ float bfhi(unsigned int d){ return __uint_as_float(d & 0xffff0000u); }

// ---------------- CSR build (group edges by destination = col) ----------------
__global__ __launch_bounds__(256) void hist_kernel(const int* __restrict__ ei, int* __restrict__ cnt){
  int k = blockIdx.x*256 + threadIdx.x;
  if (k >= N_TOT) return;
  int c = (k < N_EDGES) ? ei[N_EDGES + k] : (k - N_EDGES);
  atomicAdd(&cnt[c], 1);
}

// hierarchical scan: A) per-1024-block sums  B) scan 49 partials  C) per-block scan + base
__global__ __launch_bounds__(1024) void scanA_kernel(const int* __restrict__ cnt, int* __restrict__ psum){
  __shared__ int wsum[16];
  int tid = threadIdx.x, i = blockIdx.x*1024 + tid;
  int v = (i < N_NODES) ? cnt[i] : 0;
  #pragma unroll
  for (int off = 32; off; off >>= 1) v += __shfl_xor(v, off, 64);
  if ((tid & 63) == 0) wsum[tid >> 6] = v;
  __syncthreads();
  if (tid < 64) {
    int t = (tid < 16) ? wsum[tid] : 0;
    #pragma unroll
    for (int off = 8; off; off >>= 1) t += __shfl_xor(t, off, 64);
    if (tid == 0) psum[blockIdx.x] = t;
  }
}

__global__ __launch_bounds__(64) void scanB_kernel(int* __restrict__ psum, int nparts){
  int lane = threadIdx.x;
  int v = (lane < nparts) ? psum[lane] : 0;
  #pragma unroll
  for (int off = 1; off < 64; off <<= 1) {
    int t = __shfl_up(v, off, 64);
    if (lane >= off) v += t;
  }
  int e = __shfl_up(v, 1, 64);
  if (lane == 0) e = 0;
  if (lane < nparts) psum[lane] = e;
}

__global__ __launch_bounds__(1024) void scanC_kernel(const int* __restrict__ cnt, const int* __restrict__ psum,
                                                     int* __restrict__ offs, int* __restrict__ cursor){
  __shared__ int sm[1024];
  int tid = threadIdx.x, b = blockIdx.x, i = b*1024 + tid;
  int v = (i < N_NODES) ? cnt[i] : 0;
  sm[tid] = v;
  __syncthreads();
  for (int off = 1; off < 1024; off <<= 1) {
    int t = (tid >= off) ? sm[tid - off] : 0;
    __syncthreads();
    sm[tid] += t;
    __syncthreads();
  }
  if (i < N_NODES) {
    int e = psum[b] + sm[tid] - v;
    offs[i] = e; cursor[i] = e;
  }
  if (b == 0 && tid == 0) offs[N_NODES] = N_TOT;
}

__global__ __launch_bounds__(256) void scatter_kernel(const int* __restrict__ ei,
                                                      int* __restrict__ cursor,
                                                      int* __restrict__ srcs){
  int k = blockIdx.x*256 + threadIdx.x;
  if (k >= N_TOT) return;
  int r, c;
  if (k < N_EDGES) { r = ei[k]; c = ei[N_EDGES + k]; } else { r = c = k - N_EDGES; }
  int pos = atomicAdd(&cursor[c], 1);
  srcs[pos] = r;
}

// ---------------- GEMM1: h1pre = x @ W1  [50000,64]x[64,256], fused al1, 16 nodes/block ----------------
__global__ __launch_bounds__(256) void gemm1_kernel(const float* __restrict__ x, const float* __restrict__ W1,
    const float* __restrict__ a1s, const float* __restrict__ a1d,
    bf16* __restrict__ h1pre, float* __restrict__ al1s, float* __restrict__ al1d){
  __shared__ __align__(16) float lx[64*16];          // [k][m], 4KB
  int tid = threadIdx.x;
  int n0  = blockIdx.x * 16;
  for (int i = tid; i < 1024; i += 256) {
    int m = i >> 6, k = i & 63;
    lx[k*16 + m] = x[(size_t)(n0 + m)*64 + k];
  }
  __syncthreads();
  float acc[16];
  #pragma unroll
  for (int m = 0; m < 16; m++) acc[m] = 0.f;
  #pragma unroll 2
  for (int k = 0; k < 64; k++) {
    float w = W1[k*256 + tid];
    const float4* xp = (const float4*)&lx[k*16];
    #pragma unroll
    for (int q = 0; q < 4; q++) {
      float4 xa = xp[q];
      acc[4*q+0] = fmaf(w, xa.x, acc[4*q+0]);
      acc[4*q+1] = fmaf(w, xa.y, acc[4*q+1]);
      acc[4*q+2] = fmaf(w, xa.z, acc[4*q+2]);
      acc[4*q+3] = fmaf(w, xa.w, acc[4*q+3]);
    }
  }
  float as = a1s[tid], ad = a1d[tid];
  int lane = tid & 63, wave = tid >> 6;   // wave == head
  #pragma unroll
  for (int m = 0; m < 16; m++) {
    h1pre[(size_t)(n0 + m)*256 + tid] = f2b(acc[m]);
    float ps = acc[m]*as, pd = acc[m]*ad;
    #pragma unroll
    for (int off = 32; off; off >>= 1) { ps += __shfl_xor(ps, off, 64); pd += __shfl_xor(pd, off, 64); }
    if (lane == 0) { al1s[(n0 + m)*4 + wave] = ps; al1d[(n0 + m)*4 + wave] = pd; }
  }
}

// ------- Attention layer 1 (H=4,C=64) + split-K GEMM2 + al2; 8 waves / 8 nodes per block -------
__global__ __launch_bounds__(512) void attn1_kernel(const bf16* __restrict__ h1pre,
    const float* __restrict__ al1s, const float* __restrict__ al1d,
    const int* __restrict__ offs, const int* __restrict__ srcs,
    const float* __restrict__ b1, const float* __restrict__ W2,
    const float* __restrict__ a2s, const float* __restrict__ a2d,
    bf16* __restrict__ h2pre, float* __restrict__ al2s, float* __restrict__ al2d){
  __shared__ __align__(16) float sh1[8][256];            // 8KB: h1 rows
  __shared__ __align__(16) float upool[8*MAXD*4];        // 16KB: ebuf, then gemm partials
  __shared__ int sbuf[8][MAXD];                          // 4KB: staged srcs
  float (*ebuf)[MAXD][4] = (float (*)[MAXD][4])upool;
  float (*pbuf)[8][64]   = (float (*)[8][64])upool;

  int wave = threadIdx.x >> 6, lane = threadIdx.x & 63;
  int n = blockIdx.x*8 + wave;          // 50000 % 8 == 0: no tail
  int start = offs[n], end = offs[n+1];
  int deg = end - start;
  float4 aldv = *(const float4*)(al1d + (size_t)n*4);
  float ald0 = aldv.x, ald1 = aldv.y, ald2 = aldv.z, ald3 = aldv.w;

  // pass1: gather als, compute e (lrelu), stage e + src, online lane max
  float mx0 = -3e38f, mx1 = -3e38f, mx2 = -3e38f, mx3 = -3e38f;
  {
    int idx = lane;
    for (int j = start + lane; j < end; j += 64, idx += 64) {
      int r = srcs[j];
      float4 als = *(const float4*)(al1s + (size_t)r*4);
      float e0 = als.x + ald0; e0 = e0 >= 0.f ? e0 : 0.2f*e0; mx0 = fmaxf(mx0, e0);
      float e1 = als.y + ald1; e1 = e1 >= 0.f ? e1 : 0.2f*e1; mx1 = fmaxf(mx1, e1);
      float e2 = als.z + ald2; e2 = e2 >= 0.f ? e2 : 0.2f*e2; mx2 = fmaxf(mx2, e2);
      float e3 = als.w + ald3; e3 = e3 >= 0.f ? e3 : 0.2f*e3; mx3 = fmaxf(mx3, e3);
      if (idx < MAXD) {
        sbuf[wave][idx] = r;
        *(float4*)&ebuf[wave][idx][0] = make_float4(e0, e1, e2, e3);
      }
    }
  }
  #pragma unroll
  for (int off = 32; off; off >>= 1) {
    mx0 = fmaxf(mx0, __shfl_xor(mx0, off, 64));
    mx1 = fmaxf(mx1, __shfl_xor(mx1, off, 64));
    mx2 = fmaxf(mx2, __shfl_xor(mx2, off, 64));
    mx3 = fmaxf(mx3, __shfl_xor(mx3, off, 64));
  }

  // pass2: p = exp(e - m) written back; lane sums
  float s0 = 0.f, s1 = 0.f, s2 = 0.f, s3 = 0.f;
  {
    int lim = deg < MAXD ? deg : MAXD;
    for (int idx = lane; idx < lim; idx += 64) {
      float4 e = *(const float4*)&ebuf[wave][idx][0];
      float p0 = __expf(e.x - mx0); s0 += p0;
      float p1 = __expf(e.y - mx1); s1 += p1;
      float p2 = __expf(e.z - mx2); s2 += p2;
      float p3 = __expf(e.w - mx3); s3 += p3;
      *(float4*)&ebuf[wave][idx][0] = make_float4(p0, p1, p2, p3);
    }
    for (int j = start + MAXD + lane; j < end; j += 64) {  // rare overflow tail
      int r = srcs[j];
      float4 als = *(const float4*)(al1s + (size_t)r*4);
      float e0 = als.x + ald0; e0 = e0 >= 0.f ? e0 : 0.2f*e0; s0 += __expf(e0 - mx0);
      float e1 = als.y + ald1; e1 = e1 >= 0.f ? e1 : 0.2f*e1; s1 += __expf(e1 - mx1);
      float e2 = als.z + ald2; e2 = e2 >= 0.f ? e2 : 0.2f*e2; s2 += __expf(e2 - mx2);
      float e3 = als.w + ald3; e3 = e3 >= 0.f ? e3 : 0.2f*e3; s3 += __expf(e3 - mx3);
    }
  }
  #pragma unroll
  for (int off = 32; off; off >>= 1) {
    s0 += __shfl_xor(s0, off, 64);
    s1 += __shfl_xor(s1, off, 64);
    s2 += __shfl_xor(s2, off, 64);
    s3 += __shfl_xor(s3, off, 64);
  }
  float inv0 = 1.f/(s0 + 1e-16f), inv1 = 1.f/(s1 + 1e-16f);
  float inv2 = 1.f/(s2 + 1e-16f), inv3 = 1.f/(s3 + 1e-16f);

  // serial aggregation, remapped: lane -> head h=lane>>4, ch-group g=lane&15 (4 ch each).
  // one dwordx2 per edge per lane; wave covers the full 512B row in one instruction.
  int g = lane & 15, h = lane >> 4;
  float acc0 = 0.f, acc1 = 0.f, acc2 = 0.f, acc3 = 0.f;
  {
    int lim = deg < MAXD ? deg : MAXD;
    const unsigned int* base = (const unsigned int*)h1pre;  // dword view
    int coff = (h*64 + g*4) >> 1;                           // dword offset in row
    #pragma unroll 2
    for (int jj = 0; jj < lim; ++jj) {
      int r = sbuf[wave][jj];
      float p = ebuf[wave][jj][h];
      uint2 d = *(const uint2*)(base + (size_t)r*128 + coff);
      acc0 = fmaf(p, bflo(d.x), acc0);
      acc1 = fmaf(p, bfhi(d.x), acc1);
      acc2 = fmaf(p, bflo(d.y), acc2);
      acc3 = fmaf(p, bfhi(d.y), acc3);
    }
    if (deg > MAXD) {       // rare overflow tail
      float mxh  = (h==0)?mx0:(h==1)?mx1:(h==2)?mx2:mx3;
      float aldh = (h==0)?ald0:(h==1)?ald1:(h==2)?ald2:ald3;
      for (int jj = MAXD; jj < deg; ++jj) {
        int r = srcs[start + jj];
        float e = al1s[(size_t)r*4 + h] + aldh; e = e >= 0.f ? e : 0.2f*e;
        float p = __expf(e - mxh);
        uint2 d = *(const uint2*)(base + (size_t)r*128 + coff);
        acc0 = fmaf(p, bflo(d.x), acc0);
        acc1 = fmaf(p, bfhi(d.x), acc1);
        acc2 = fmaf(p, bflo(d.y), acc2);
        acc3 = fmaf(p, bfhi(d.y), acc3);
      }
    }
  }
  // h1 row (post-bias ELU) into LDS, channels h*64+g*4 .. +3
  {
    float invh = (h==0)?inv0:(h==1)?inv1:(h==2)?inv2:inv3;
    float4 bv = *(const float4*)(b1 + h*64 + g*4);
    float o0 = acc0*invh + bv.x; o0 = o0 > 0.f ? o0 : expm1f(o0);
    float o1 = acc1*invh + bv.y; o1 = o1 > 0.f ? o1 : expm1f(o1);
    float o2 = acc2*invh + bv.z; o2 = o2 > 0.f ? o2 : expm1f(o2);
    float o3 = acc3*invh + bv.w; o3 = o3 > 0.f ? o3 : expm1f(o3);
    *(float4*)&sh1[wave][h*64 + g*4] = make_float4(o0, o1, o2, o3);
  }
  __syncthreads();   // sh1 complete; ebuf dead -> pbuf reuse is safe past this point

  // split-K GEMM2: wave w handles k in [w*32, w*32+32); W2 read ONCE per block
  {
    int col = lane, k0 = wave*32;
    float part[8];
    #pragma unroll
    for (int m = 0; m < 8; m++) part[m] = 0.f;
    #pragma unroll
    for (int kk = 0; kk < 32; kk += 4) {
      float w0 = W2[(k0+kk+0)*64 + col];
      float w1 = W2[(k0+kk+1)*64 + col];
      float w2 = W2[(k0+kk+2)*64 + col];
      float w3 = W2[(k0+kk+3)*64 + col];
      #pragma unroll
      for (int m = 0; m < 8; m++) {
        float4 hv = *(const float4*)&sh1[m][k0+kk];
        part[m] = fmaf(hv.x, w0, fmaf(hv.y, w1, fmaf(hv.z, w2, fmaf(hv.w, w3, part[m]))));
      }
    }
    __syncthreads();   // ensure all ebuf readers done before pbuf overwrite
    #pragma unroll
    for (int m = 0; m < 8; m++) pbuf[wave][m][col] = part[m];
  }
  __syncthreads();

  // final: wave w owns node w; reduce partials over 8 k-groups
  {
    int col = lane;
    float acc = 0.f;
    #pragma unroll
    for (int gg = 0; gg < 8; gg++) acc += pbuf[gg][wave][col];
    h2pre[(size_t)n*64 + col] = f2b(acc);
    float ps = acc * a2s[col], pd = acc * a2d[col];
    #pragma unroll
    for (int off = 32; off; off >>= 1) { ps += __shfl_xor(ps, off, 64); pd += __shfl_xor(pd, off, 64); }
    if (col == 0) { al2s[n] = ps; al2d[n] = pd; }
  }
}

// ---------------- Attention layer 2 (H=1) + node head + u/v; 8 waves/block ----------------
__global__ __launch_bounds__(512) void attn2_kernel(const bf16* __restrict__ h2pre,
    const float* __restrict__ al2s, const float* __restrict__ al2d,
    const int* __restrict__ offs, const int* __restrict__ srcs,
    const float* __restrict__ b2, const float* __restrict__ Wn, const float* __restrict__ bn,
    const float* __restrict__ We,
    float* __restrict__ u, float* __restrict__ v, float* __restrict__ node_out){
  __shared__ float ebuf[8][MAXD];               // 4KB
  __shared__ int   sbuf[8][MAXD];               // 4KB
  __shared__ __align__(16) float sh[8][64];     // 2KB
  int wave = threadIdx.x >> 6, lane = threadIdx.x & 63;
  int n = blockIdx.x*8 + wave;        // exact
  int start = offs[n], end = offs[n+1];
  int deg = end - start;
  float ald = al2d[n];

  float mx = -3e38f;
  {
    int idx = lane;
    for (int j = start + lane; j < end; j += 64, idx += 64) {
      int r = srcs[j];
      float t = al2s[r] + ald; t = t >= 0.f ? t : 0.2f*t;
      mx = fmaxf(mx, t);
      if (idx < MAXD) { sbuf[wave][idx] = r; ebuf[wave][idx] = t; }
    }
  }
  #pragma unroll
  for (int off = 32; off; off >>= 1) mx = fmaxf(mx, __shfl_xor(mx, off, 64));

  float sm = 0.f;
  {
    int lim = deg < MAXD ? deg : MAXD;
    for (int idx = lane; idx < lim; idx += 64) {
      float p = __expf(ebuf[wave][idx] - mx); ebuf[wave][idx] = p; sm += p;
    }
    for (int j = start + MAXD + lane; j < end; j += 64) {
      float t = al2s[srcs[j]] + ald; t = t >= 0.f ? t : 0.2f*t;
      sm += __expf(t - mx);
    }
  }
  #pragma unroll
  for (int off = 32; off; off >>= 1) sm += __shfl_xor(sm, off, 64);
  float inv = 1.f/(sm + 1e-16f);

  // aggregation: 4 edges/iteration; lane -> (edge-sub eg=lane>>4, ch-group g=lane&15)
  int g = lane & 15, eg = lane >> 4;
  float acc0 = 0.f, acc1 = 0.f, acc2 = 0.f, acc3 = 0.f;
  {
    int lim = deg < MAXD ? deg : MAXD;
    const unsigned int* base = (const unsigned int*)h2pre;  // dword view
    int coff = (g*4) >> 1;
    for (int jj = 0; jj < lim; jj += 4) {
      int idx = jj + eg;
      bool ok = idx < lim;
      int idxs = ok ? idx : 0;
      float p = ok ? ebuf[wave][idxs] : 0.f;
      int r = sbuf[wave][idxs];
      uint2 d = *(const uint2*)(base + (size_t)r*32 + coff);
      acc0 = fmaf(p, bflo(d.x), acc0);
      acc1 = fmaf(p, bfhi(d.x), acc1);
      acc2 = fmaf(p, bflo(d.y), acc2);
      acc3 = fmaf(p, bfhi(d.y), acc3);
    }
    if (deg > MAXD) {     // rare overflow tail: only eg==0 contributes
      for (int jj = MAXD; jj < deg; ++jj) {
        int r = srcs[start + jj];
        float t = al2s[r] + ald; t = t >= 0.f ? t : 0.2f*t;
        float p = (eg == 0) ? __expf(t - mx) : 0.f;
        uint2 d = *(const uint2*)(base + (size_t)r*32 + coff);
        acc0 = fmaf(p, bflo(d.x), acc0);
        acc1 = fmaf(p, bfhi(d.x), acc1);
        acc2 = fmaf(p, bflo(d.y), acc2);
        acc3 = fmaf(p, bfhi(d.y), acc3);
      }
    }
  }
  // fold the 4 edge-groups (xor butterfly over lane bits 4,5)
  acc0 += __shfl_xor(acc0, 16, 64); acc0 += __shfl_xor(acc0, 32, 64);
  acc1 += __shfl_xor(acc1, 16, 64); acc1 += __shfl_xor(acc1, 32, 64);
  acc2 += __shfl_xor(acc2, 16, 64); acc2 += __shfl_xor(acc2, 32, 64);
  acc3 += __shfl_xor(acc3, 16, 64); acc3 += __shfl_xor(acc3, 32, 64);

  float4 b2v = *(const float4*)(b2 + g*4);
  float o0 = acc0*inv + b2v.x; o0 = o0 > 0.f ? o0 : expm1f(o0);
  float o1 = acc1*inv + b2v.y; o1 = o1 > 0.f ? o1 : expm1f(o1);
  float o2 = acc2*inv + b2v.z; o2 = o2 > 0.f ? o2 : expm1f(o2);
  float o3 = acc3*inv + b2v.w; o3 = o3 > 0.f ? o3 : expm1f(o3);

  // u[n] = h2 . We[0:64], v[n] = h2 . We[64:128] (each channel counted 4x -> *0.25)
  float4 weu = *(const float4*)(We + g*4);
  float4 wev = *(const float4*)(We + 64 + g*4);
  float pu = o0*weu.x + o1*weu.y + o2*weu.z + o3*weu.w;
  float pv = o0*wev.x + o1*wev.y + o2*wev.z + o3*wev.w;
  #pragma unroll
  for (int off = 32; off; off >>= 1) { pu += __shfl_xor(pu, off, 64); pv += __shfl_xor(pv, off, 64); }
  if (lane == 0) { u[n] = pu*0.25f; v[n] = pv*0.25f; }

  if (eg == 0) *(float4*)&sh[wave][g*4] = make_float4(o0, o1, o2, o3);
  __syncthreads();

  // node_out = h2 @ Wn + bn  (Wn: [64,32]); lanes split k-range in halves
  int jcol = lane & 31, half = lane >> 5;
  float a2 = 0.f;
  #pragma unroll 8
  for (int k2 = 0; k2 < 32; k2++) {
    int k = half*32 + k2;
    a2 = fmaf(sh[wave][k], Wn[k*32 + jcol], a2);
  }
  a2 += __shfl_xor(a2, 32, 64);
  if (lane < 32) node_out[(size_t)n*32 + lane] = a2 + bn[jcol];
}

// ---------------- Edge head: out = u[row] + v[col] + edge_attr . We[128:144] + be ----------------
__global__ __launch_bounds__(256) void edge_kernel(const int* __restrict__ ei, const float* __restrict__ ea,
    const float* __restrict__ u, const float* __restrict__ v,
    const float* __restrict__ We, const float* __restrict__ be, float* __restrict__ out){
  int k = blockIdx.x*256 + threadIdx.x;   // grid is exact: 800000/256
  int r = ei[k], c = ei[N_EDGES + k];
  float val = u[r] + v[c] + be[0];
  const float4* wp = (const float4*)(We + 128);
  const float4* p  = (const float4*)(ea + (size_t)k*16);
  #pragma unroll
  for (int jj = 0; jj < 4; jj++) {
    float4 q = p[jj], wq = wp[jj];
    val = fmaf(q.x, wq.x, val);
    val = fmaf(q.y, wq.y, val);
    val = fmaf(q.z, wq.z, val);
    val = fmaf(q.w, wq.w, val);
  }
  out[k] = val;
}

extern "C" void kernel_launch(void* const* d_in, const int* in_sizes, int n_in,
                              void* d_out, int out_size, void* d_ws, size_t ws_size,
                              hipStream_t stream) {
  const float* x   = (const float*)d_in[0];
  const int*   ei  = (const int*)d_in[1];
  const float* ea  = (const float*)d_in[2];
  const float* W1  = (const float*)d_in[3];
  const float* a1s = (const float*)d_in[4];
  const float* a1d = (const float*)d_in[5];
  const float* b1  = (const float*)d_in[6];
  const float* W2  = (const float*)d_in[7];
  const float* a2s = (const float*)d_in[8];
  const float* a2d = (const float*)d_in[9];
  const float* b2  = (const float*)d_in[10];
  const float* Wn  = (const float*)d_in[11];
  const float* bn  = (const float*)d_in[12];
  const float* We  = (const float*)d_in[13];
  const float* be  = (const float*)d_in[14];
  float* out = (float*)d_out;

  // ---- workspace layout, peak 38,400,224 B, all offsets 16B-aligned (known-good size) ----
  char* w = (char*)d_ws;
  int*   offs   = (int*)(w);                        //       0 .. 200,016
  int*   cnt    = (int*)(w + 200016);               // 200,016 .. 400,016
  int*   cursor = (int*)(w + 400016);               // 400,016 .. 600,016
  int*   srcs   = (int*)(w + 600016);               // 600,016 .. 4,000,016
  float* al1s   = (float*)(w + 4000016);            // [N,4] fp32, .. 4,800,016
  float* al1d   = (float*)(w + 4800016);            // [N,4] fp32, .. 5,600,016
  float* al2s   = (float*)(w + 5600016);            // [N] fp32,  .. 5,800,016
  float* al2d   = (float*)(w + 5800016);            // .. 6,000,016
  float* uu     = (float*)(w + 6000016);            // .. 6,200,016
  float* vv     = (float*)(w + 6200016);            // .. 6,400,016
  bf16*  h2pre  = (bf16*)(w + 6400016);             // [N,64] bf16, .. 12,800,016
  bf16*  h1pre  = (bf16*)(w + 12800016);            // [N,256] bf16, .. 38,400,016
  int*   psum   = (int*)(w + 38400016);             // 49 partials (16B-aligned)

  const int NPART = (N_NODES + 1023) / 1024;        // 49

  hipMemsetAsync(cnt, 0, (size_t)N_NODES * 4, stream);
  hist_kernel   <<<(N_TOT + 255)/256, 256, 0, stream>>>(ei, cnt);
  scanA_kernel  <<<NPART, 1024, 0, stream>>>(cnt, psum);
  scanB_kernel  <<<1, 64, 0, stream>>>(psum, NPART);
  scanC_kernel  <<<NPART, 1024, 0, stream>>>(cnt, psum, offs, cursor);
  scatter_kernel<<<(N_TOT + 255)/256, 256, 0, stream>>>(ei, cursor, srcs);
  gemm1_kernel  <<<N_NODES/16, 256, 0, stream>>>(x, W1, a1s, a1d, h1pre, al1s, al1d);
  attn1_kernel  <<<N_NODES/8, 512, 0, stream>>>(h1pre, al1s, al1d, offs, srcs, b1, W2,
                                                a2s, a2d, h2pre, al2s, al2d);
  attn2_kernel  <<<N_NODES/8, 512, 0, stream>>>(h2pre, al2s, al2d, offs, srcs, b2, Wn, bn, We,
                                                uu, vv, out);
  edge_kernel   <<<N_EDGES/256, 256, 0, stream>>>(ei, ea, uu, vv, We, be, out + (size_t)N_NODES*32);
}